// Round 1
// baseline (2700.092 us; speedup 1.0000x reference)
//
#include <hip/hip_runtime.h>
#include <math.h>

// Problem constants
#define BB 8
#define CC 512
#define HWN 16384
#define KK 150
#define NSEG 16
#define SEGN (HWN / NSEG)   // 1024

// ---------------------------------------------------------------------------
// G1: A[b][k][n] = sum_c cls[k][c] * x[b][c][n]   (coupled_attn)
// block: 256 thr; tile: 128 n x all 150 k; c-chunks of 32.
// thread: nl = tid&63 handles n0+nl and n0+64+nl; kg = tid>>6 handles 38 k.
// cls reads are wave-uniform (kg==wave id) -> LDS broadcast (free).
// ---------------------------------------------------------------------------
__global__ __launch_bounds__(256) void g1_attn(const float* __restrict__ x,
                                               const float* __restrict__ cls,
                                               float* __restrict__ A) {
  const int n0 = blockIdx.x * 128;
  const int b = blockIdx.y;
  const int tid = threadIdx.x;
  const int nl = tid & 63;
  const int kg = tid >> 6;
  const int k0 = kg * 38;
  __shared__ float xs[32 * 128];   // [c][n]
  __shared__ float cs[KK * 32];    // [k][c]
  float acc[38][2];
#pragma unroll
  for (int j = 0; j < 38; j++) { acc[j][0] = 0.f; acc[j][1] = 0.f; }
  const float* xb = x + (size_t)b * CC * HWN;
  for (int c0 = 0; c0 < CC; c0 += 32) {
    __syncthreads();
    for (int e = tid; e < 32 * 128; e += 256) {
      int cc = e >> 7, nn = e & 127;
      xs[e] = xb[(size_t)(c0 + cc) * HWN + n0 + nn];
    }
    for (int e = tid; e < KK * 32; e += 256) {
      int k = e >> 5, c = e & 31;
      cs[e] = cls[k * CC + c0 + c];
    }
    __syncthreads();
#pragma unroll
    for (int s = 0; s < 32; s += 8) {
      float xr0[8], xr1[8];
#pragma unroll
      for (int i = 0; i < 8; i++) {
        xr0[i] = xs[(s + i) * 128 + nl];
        xr1[i] = xs[(s + i) * 128 + 64 + nl];
      }
#pragma unroll
      for (int j = 0; j < 38; j++) {
        if (k0 + j < KK) {
          const float* cr = &cs[(k0 + j) * 32 + s];
#pragma unroll
          for (int i = 0; i < 8; i++) {
            acc[j][0] = fmaf(cr[i], xr0[i], acc[j][0]);
            acc[j][1] = fmaf(cr[i], xr1[i], acc[j][1]);
          }
        }
      }
    }
  }
#pragma unroll
  for (int j = 0; j < 38; j++) {
    if (k0 + j < KK) {
      size_t base = ((size_t)(b * KK + k0 + j)) * HWN + n0;
      A[base + nl] = acc[j][0];
      A[base + 64 + nl] = acc[j][1];
    }
  }
}

// ---------------------------------------------------------------------------
// G2a: per-(b,k) row max and sum(exp) over n  (cls_attn softmax stats)
// ---------------------------------------------------------------------------
__global__ __launch_bounds__(256) void g2a_rowstats(const float* __restrict__ A,
                                                    float* __restrict__ rowmax,
                                                    float* __restrict__ rowsum) {
  const int bk = blockIdx.x;
  const float* row = A + (size_t)bk * HWN;
  __shared__ float red[8];
  const int tid = threadIdx.x, lane = tid & 63, w = tid >> 6;
  float m = -INFINITY;
  for (int i = tid; i < HWN; i += 256) m = fmaxf(m, row[i]);
#pragma unroll
  for (int o = 32; o > 0; o >>= 1) m = fmaxf(m, __shfl_down(m, o, 64));
  if (lane == 0) red[w] = m;
  __syncthreads();
  if (tid == 0) red[4] = fmaxf(fmaxf(red[0], red[1]), fmaxf(red[2], red[3]));
  __syncthreads();
  const float mm = red[4];
  float s = 0.f;
  for (int i = tid; i < HWN; i += 256) s += __expf(row[i] - mm);
#pragma unroll
  for (int o = 32; o > 0; o >>= 1) s += __shfl_down(s, o, 64);
  if (lane == 0) red[w] = s;
  __syncthreads();
  if (tid == 0) {
    rowmax[bk] = mm;
    rowsum[bk] = red[0] + red[1] + red[2] + red[3];
  }
}

// ---------------------------------------------------------------------------
// G2b: per-(b,n) max and sum(exp) over k  (pos_attn softmax stats)
// ---------------------------------------------------------------------------
__global__ __launch_bounds__(256) void g2b_colstats(const float* __restrict__ A,
                                                    float* __restrict__ colmax,
                                                    float* __restrict__ colsum) {
  const int b = blockIdx.y;
  const int n = blockIdx.x * 256 + threadIdx.x;
  const float* Ab = A + (size_t)b * KK * HWN + n;
  float m = -INFINITY;
  for (int k = 0; k < KK; k++) m = fmaxf(m, Ab[(size_t)k * HWN]);
  float s = 0.f;
  for (int k = 0; k < KK; k++) s += __expf(Ab[(size_t)k * HWN] - m);
  colmax[b * HWN + n] = m;
  colsum[b * HWN + n] = s;
}

// ---------------------------------------------------------------------------
// G3: partial Sc: Scp[b][seg][k][c] = sum_{n in seg} exp(A[b][k][n]-rowmax)*x[b][c][n]
// block: 256 thr; tile: all 150 k x 128 c over one 1024-n segment, n-chunks of 32.
// thread: cl = tid&63 -> c pair; kg -> 38 k.  E reads wave-uniform broadcast.
// ---------------------------------------------------------------------------
__global__ __launch_bounds__(256) void g3_scpart(const float* __restrict__ x,
                                                 const float* __restrict__ A,
                                                 const float* __restrict__ rowmax,
                                                 float* __restrict__ Scp) {
  const int c0 = blockIdx.x * 128;
  const int seg = blockIdx.y;
  const int b = blockIdx.z;
  const int tid = threadIdx.x;
  const int cl = tid & 63;
  const int kg = tid >> 6;
  const int k0 = kg * 38;
  const int ns0 = seg * SEGN;
  __shared__ float es[KK * 32];        // [k][n]
  __shared__ float xs2[128 * 33];      // [c][n], pad 33
  float acc[38][2];
#pragma unroll
  for (int j = 0; j < 38; j++) { acc[j][0] = 0.f; acc[j][1] = 0.f; }
  const float* xb = x + (size_t)b * CC * HWN;
  for (int nc0 = 0; nc0 < SEGN; nc0 += 32) {
    __syncthreads();
    for (int e = tid; e < KK * 32; e += 256) {
      int k = e >> 5, n = e & 31;
      float a = A[((size_t)(b * KK + k)) * HWN + ns0 + nc0 + n];
      es[e] = __expf(a - rowmax[b * KK + k]);
    }
    for (int e = tid; e < 128 * 32; e += 256) {
      int n = e & 31, c = e >> 5;
      xs2[c * 33 + n] = xb[(size_t)(c0 + c) * HWN + ns0 + nc0 + n];
    }
    __syncthreads();
#pragma unroll
    for (int s = 0; s < 32; s += 8) {
      float xr0[8], xr1[8];
#pragma unroll
      for (int i = 0; i < 8; i++) {
        xr0[i] = xs2[cl * 33 + s + i];
        xr1[i] = xs2[(cl + 64) * 33 + s + i];
      }
#pragma unroll
      for (int j = 0; j < 38; j++) {
        if (k0 + j < KK) {
          const float* er = &es[(k0 + j) * 32 + s];
#pragma unroll
          for (int i = 0; i < 8; i++) {
            acc[j][0] = fmaf(er[i], xr0[i], acc[j][0]);
            acc[j][1] = fmaf(er[i], xr1[i], acc[j][1]);
          }
        }
      }
    }
  }
#pragma unroll
  for (int j = 0; j < 38; j++) {
    if (k0 + j < KK) {
      size_t base = (((size_t)(b * NSEG + seg)) * KK + k0 + j) * CC + c0;
      Scp[base + cl] = acc[j][0];
      Scp[base + 64 + cl] = acc[j][1];
    }
  }
}

// ---------------------------------------------------------------------------
// G5: Sc[bk][c] = (sum_seg Scp) / rowsum[bk]
// ---------------------------------------------------------------------------
__global__ __launch_bounds__(256) void g5_reduce(const float* __restrict__ Scp,
                                                 const float* __restrict__ rowsum,
                                                 float* __restrict__ Sc) {
  const int bk = blockIdx.x;
  const int b = bk / KK, k = bk % KK;
  const float inv = 1.0f / rowsum[bk];
  for (int c = threadIdx.x; c < CC; c += 256) {
    float s = 0.f;
    for (int seg = 0; seg < NSEG; seg++)
      s += Scp[(((size_t)(b * NSEG + seg)) * KK + k) * CC + c];
    Sc[(size_t)bk * CC + c] = s * inv;
  }
}

// ---------------------------------------------------------------------------
// G4a: AC[bk][j] = cls[k][j] + sum_c Sc[bk][c]*Wc[j][c]   (wave per 4 outputs)
// ---------------------------------------------------------------------------
__global__ __launch_bounds__(256) void g4a_ac(const float* __restrict__ Sc,
                                              const float* __restrict__ Wc,
                                              const float* __restrict__ cls,
                                              float* __restrict__ AC) {
  const int bk = blockIdx.y;
  const int k = bk % KK;
  const int w = threadIdx.x >> 6, lane = threadIdx.x & 63;
  const int j0 = (blockIdx.x * 4 + w) * 4;
  const float4* arow = (const float4*)(Sc + (size_t)bk * CC);
  float4 a0 = arow[lane], a1 = arow[64 + lane];
#pragma unroll
  for (int jj = 0; jj < 4; jj++) {
    const float4* brow = (const float4*)(Wc + (size_t)(j0 + jj) * CC);
    float4 b0 = brow[lane], b1 = brow[64 + lane];
    float d = a0.x * b0.x + a0.y * b0.y + a0.z * b0.z + a0.w * b0.w +
              a1.x * b1.x + a1.y * b1.y + a1.z * b1.z + a1.w * b1.w;
#pragma unroll
    for (int o = 32; o > 0; o >>= 1) d += __shfl_down(d, o, 64);
    if (lane == 0) AC[(size_t)bk * CC + j0 + jj] = cls[k * CC + j0 + jj] + d;
  }
}

// ---------------------------------------------------------------------------
// G4b: CWf[k][j] = sum_c cls[k][c]*Wf[j][c]
// ---------------------------------------------------------------------------
__global__ __launch_bounds__(256) void g4b_cwf(const float* __restrict__ cls,
                                               const float* __restrict__ Wf,
                                               float* __restrict__ CWf) {
  const int k = blockIdx.y;
  const int w = threadIdx.x >> 6, lane = threadIdx.x & 63;
  const int j0 = (blockIdx.x * 4 + w) * 4;
  const float4* arow = (const float4*)(cls + (size_t)k * CC);
  float4 a0 = arow[lane], a1 = arow[64 + lane];
#pragma unroll
  for (int jj = 0; jj < 4; jj++) {
    const float4* brow = (const float4*)(Wf + (size_t)(j0 + jj) * CC);
    float4 b0 = brow[lane], b1 = brow[64 + lane];
    float d = a0.x * b0.x + a0.y * b0.y + a0.z * b0.z + a0.w * b0.w +
              a1.x * b1.x + a1.y * b1.y + a1.z * b1.z + a1.w * b1.w;
#pragma unroll
    for (int o = 32; o > 0; o >>= 1) d += __shfl_down(d, o, 64);
    if (lane == 0) CWf[(size_t)k * CC + j0 + jj] = d;
  }
}

// ---------------------------------------------------------------------------
// G4c: M[b][k1][k2] = sum_c CWf[k1][c]*AC[b*K+k2][c]
// ---------------------------------------------------------------------------
__global__ __launch_bounds__(256) void g4c_m(const float* __restrict__ CWf,
                                             const float* __restrict__ AC,
                                             float* __restrict__ Mm) {
  const int k1 = blockIdx.y;
  const int b = blockIdx.z;
  const int w = threadIdx.x >> 6, lane = threadIdx.x & 63;
  const int k20 = (blockIdx.x * 4 + w) * 4;
  const float4* arow = (const float4*)(CWf + (size_t)k1 * CC);
  float4 a0 = arow[lane], a1 = arow[64 + lane];
#pragma unroll
  for (int jj = 0; jj < 4; jj++) {
    int k2 = k20 + jj;
    if (k2 >= KK) break;
    const float4* brow = (const float4*)(AC + (size_t)(b * KK + k2) * CC);
    float4 b0 = brow[lane], b1 = brow[64 + lane];
    float d = a0.x * b0.x + a0.y * b0.y + a0.z * b0.z + a0.w * b0.w +
              a1.x * b1.x + a1.y * b1.y + a1.z * b1.z + a1.w * b1.w;
#pragma unroll
    for (int o = 32; o > 0; o >>= 1) d += __shfl_down(d, o, 64);
    if (lane == 0) Mm[((size_t)(b * KK) + k1) * KK + k2] = d;
  }
}

// ---------------------------------------------------------------------------
// G6: masks[n][k] = sum_c x[c][n]*AC[k][c]  +  sum_k' P[k'][n]*M[k'][k]
//     then LayerNorm over k, write out[b][k][n].
// Same tiling as G1 (128 n x 150 k). P computed on the fly from A + col stats.
// M reads are wave-uniform -> scalar loads (readfirstlane on kg).
// ---------------------------------------------------------------------------
__global__ __launch_bounds__(256) void g6_final(
    const float* __restrict__ x, const float* __restrict__ A,
    const float* __restrict__ colmax, const float* __restrict__ colsum,
    const float* __restrict__ AC, const float* __restrict__ Mm,
    const float* __restrict__ gamma, const float* __restrict__ beta,
    float* __restrict__ out) {
  const int n0 = blockIdx.x * 128;
  const int b = blockIdx.y;
  const int tid = threadIdx.x;
  const int nl = tid & 63;
  const int kg = tid >> 6;
  const int k0 = kg * 38;
  const int kgs = __builtin_amdgcn_readfirstlane(kg);
  __shared__ float s1buf[32 * 128];   // P chunk, then x chunk
  __shared__ float s2buf[KK * 32];    // AC chunk, then LN reductions
  float acc[38][2];
#pragma unroll
  for (int j = 0; j < 38; j++) { acc[j][0] = 0.f; acc[j][1] = 0.f; }

  // ---- part 2: acc += P^T M ----
  const float* Mb = Mm + (size_t)b * KK * KK;
  for (int kc = 0; kc < KK; kc += 32) {
    const int kn = (KK - kc) < 32 ? (KK - kc) : 32;
    __syncthreads();
    for (int e = tid; e < kn * 128; e += 256) {
      int kk = e >> 7, nn = e & 127;
      float a = A[((size_t)(b * KK + kc + kk)) * HWN + n0 + nn];
      float p = __expf(a - colmax[b * HWN + n0 + nn]) / colsum[b * HWN + n0 + nn];
      s1buf[kk * 128 + nn] = p;
    }
    __syncthreads();
    for (int kk = 0; kk < kn; kk++) {
      float p0 = s1buf[kk * 128 + nl];
      float p1 = s1buf[kk * 128 + 64 + nl];
      const float* Mrow = Mb + (size_t)(kc + kk) * KK + kgs * 38;
#pragma unroll
      for (int j = 0; j < 38; j++) {
        if (k0 + j < KK) {
          float m = Mrow[j];
          acc[j][0] = fmaf(p0, m, acc[j][0]);
          acc[j][1] = fmaf(p1, m, acc[j][1]);
        }
      }
    }
  }

  // ---- part 1: acc += x^T AC^T  (same structure as G1) ----
  const float* xb = x + (size_t)b * CC * HWN;
  const float* ACb = AC + (size_t)b * KK * CC;
  for (int c0 = 0; c0 < CC; c0 += 32) {
    __syncthreads();
    for (int e = tid; e < 32 * 128; e += 256) {
      int cc = e >> 7, nn = e & 127;
      s1buf[e] = xb[(size_t)(c0 + cc) * HWN + n0 + nn];
    }
    for (int e = tid; e < KK * 32; e += 256) {
      int k = e >> 5, c = e & 31;
      s2buf[e] = ACb[k * CC + c0 + c];
    }
    __syncthreads();
#pragma unroll
    for (int s = 0; s < 32; s += 8) {
      float xr0[8], xr1[8];
#pragma unroll
      for (int i = 0; i < 8; i++) {
        xr0[i] = s1buf[(s + i) * 128 + nl];
        xr1[i] = s1buf[(s + i) * 128 + 64 + nl];
      }
#pragma unroll
      for (int j = 0; j < 38; j++) {
        if (k0 + j < KK) {
          const float* cr = &s2buf[(k0 + j) * 32 + s];
#pragma unroll
          for (int i = 0; i < 8; i++) {
            acc[j][0] = fmaf(cr[i], xr0[i], acc[j][0]);
            acc[j][1] = fmaf(cr[i], xr1[i], acc[j][1]);
          }
        }
      }
    }
  }

  // ---- LayerNorm over k (150) per n ----
  float s1a = 0.f, s2a = 0.f, s1b = 0.f, s2b = 0.f;
#pragma unroll
  for (int j = 0; j < 38; j++) {
    if (k0 + j < KK) {
      s1a += acc[j][0]; s2a += acc[j][0] * acc[j][0];
      s1b += acc[j][1]; s2b += acc[j][1] * acc[j][1];
    }
  }
  __syncthreads();   // done with s2buf as AC tile
  // red layout: [kg][half][stat][nl]
  s2buf[((kg * 2 + 0) * 2 + 0) * 64 + nl] = s1a;
  s2buf[((kg * 2 + 0) * 2 + 1) * 64 + nl] = s2a;
  s2buf[((kg * 2 + 1) * 2 + 0) * 64 + nl] = s1b;
  s2buf[((kg * 2 + 1) * 2 + 1) * 64 + nl] = s2b;
  __syncthreads();
  float* stats = s2buf + 1024;   // [half][mu/inv][nl]
  if (tid < 128) {
    int h = tid >> 6, ln = tid & 63;
    float s1 = 0.f, s2 = 0.f;
    for (int g = 0; g < 4; g++) {
      s1 += s2buf[((g * 2 + h) * 2 + 0) * 64 + ln];
      s2 += s2buf[((g * 2 + h) * 2 + 1) * 64 + ln];
    }
    float mu = s1 / (float)KK;
    float var = s2 / (float)KK - mu * mu;
    stats[(h * 2 + 0) * 64 + ln] = mu;
    stats[(h * 2 + 1) * 64 + ln] = rsqrtf(var + 1e-5f);
  }
  __syncthreads();
  const float mu0 = stats[0 * 64 + nl], inv0 = stats[1 * 64 + nl];
  const float mu1 = stats[2 * 64 + nl], inv1 = stats[3 * 64 + nl];
#pragma unroll
  for (int j = 0; j < 38; j++) {
    if (k0 + j < KK) {
      int k = k0 + j;
      float g = gamma[k], be = beta[k];
      size_t base = ((size_t)(b * KK + k)) * HWN + n0;
      out[base + nl] = (acc[j][0] - mu0) * inv0 * g + be;
      out[base + 64 + nl] = (acc[j][1] - mu1) * inv1 * g + be;
    }
  }
}

// ---------------------------------------------------------------------------
extern "C" void kernel_launch(void* const* d_in, const int* in_sizes, int n_in,
                              void* d_out, int out_size, void* d_ws, size_t ws_size,
                              hipStream_t stream) {
  const float* x = (const float*)d_in[0];
  const float* cls = (const float*)d_in[1];
  const float* Wc = (const float*)d_in[2];
  const float* Wf = (const float*)d_in[3];
  const float* gam = (const float*)d_in[4];
  const float* bet = (const float*)d_in[5];
  float* out = (float*)d_out;

  float* ws = (float*)d_ws;
  float* A = ws;        ws += (size_t)BB * KK * HWN;         // 19,660,800
  float* rowmax = ws;   ws += BB * KK;                       // 1,200
  float* rowsum = ws;   ws += BB * KK;                       // 1,200
  float* colmax = ws;   ws += (size_t)BB * HWN;              // 131,072
  float* colsum = ws;   ws += (size_t)BB * HWN;              // 131,072
  float* Scp = ws;      ws += (size_t)BB * NSEG * KK * CC;   // 9,830,400
  float* Sc = ws;       ws += (size_t)BB * KK * CC;          // 614,400
  float* AC = ws;       ws += (size_t)BB * KK * CC;          // 614,400
  float* CWf = ws;      ws += (size_t)KK * CC;               // 76,800
  float* Mm = ws;       ws += (size_t)BB * KK * KK;          // 180,000
  // total ~125 MB of workspace

  g1_attn<<<dim3(HWN / 128, BB), 256, 0, stream>>>(x, cls, A);
  g2a_rowstats<<<dim3(BB * KK), 256, 0, stream>>>(A, rowmax, rowsum);
  g2b_colstats<<<dim3(HWN / 256, BB), 256, 0, stream>>>(A, colmax, colsum);
  g3_scpart<<<dim3(CC / 128, NSEG, BB), 256, 0, stream>>>(x, A, rowmax, Scp);
  g5_reduce<<<dim3(BB * KK), 256, 0, stream>>>(Scp, rowsum, Sc);
  g4b_cwf<<<dim3(CC / 16, KK), 256, 0, stream>>>(cls, Wf, CWf);
  g4a_ac<<<dim3(CC / 16, BB * KK), 256, 0, stream>>>(Sc, Wc, cls, AC);
  g4c_m<<<dim3(10, KK, BB), 256, 0, stream>>>(CWf, AC, Mm);
  g6_final<<<dim3(HWN / 128, BB), 256, 0, stream>>>(x, A, colmax, colsum, AC, Mm,
                                                    gam, bet, out);
}

// Round 2
// 1103.511 us; speedup vs baseline: 2.4468x; 2.4468x over previous
//
#include <hip/hip_runtime.h>
#include <math.h>

#define BB 8
#define CC 512
#define HWN 16384
#define KK 150
#define KP 160
#define NSEG 8
#define SEGN (HWN / NSEG)  // 2048

typedef short bf8v __attribute__((ext_vector_type(8)));
typedef float f4v __attribute__((ext_vector_type(4)));

static __device__ inline unsigned short f2b(float f) {
  unsigned u = __float_as_uint(f);
  u += 0x7fffu + ((u >> 16) & 1u);
  return (unsigned short)(u >> 16);
}
static __device__ inline float b2f(unsigned short s) {
  return __uint_as_float(((unsigned)s) << 16);
}
static __device__ inline float b2fs(short s) { return b2f((unsigned short)s); }

// ---------------------------------------------------------------------------
// t0: build cls16 [160][512] (rows >=150 zero), zero MT16, zero AC16 pad rows
// ---------------------------------------------------------------------------
__global__ __launch_bounds__(256) void t0_prep(const float* __restrict__ cls,
                                               unsigned short* __restrict__ cls16,
                                               unsigned short* __restrict__ MT16,
                                               unsigned short* __restrict__ AC16) {
  int i = blockIdx.x * 256 + threadIdx.x;
  if (i < KP * CC) {
    int k = i >> 9, c = i & 511;
    cls16[i] = (k < KK) ? f2b(cls[k * CC + c]) : 0;
  }
  if (i < BB * KP * KP) MT16[i] = 0;
  if (i < BB * (KP - KK) * CC) {
    int b = i / ((KP - KK) * CC);
    int r = i % ((KP - KK) * CC);
    int k = KK + (r >> 9);
    int c = r & 511;
    AC16[((size_t)b * KP + k) * CC + c] = 0;
  }
}

// ---------------------------------------------------------------------------
// t1: x [b][c][n] fp32 -> xT16 [b][n][c] bf16  (LDS tile transpose)
// ---------------------------------------------------------------------------
__global__ __launch_bounds__(256) void t1_transpose(const float* __restrict__ x,
                                                    unsigned short* __restrict__ xT) {
  __shared__ float ts[32][65];
  const int n0 = blockIdx.x * 64, c0 = blockIdx.y * 32, b = blockIdx.z;
  const int tid = threadIdx.x;
  const float* xb = x + (size_t)b * CC * HWN;
#pragma unroll
  for (int i = 0; i < 8; i++) {
    int e = tid + i * 256;
    int n = e & 63, c = e >> 6;
    ts[c][n] = xb[(size_t)(c0 + c) * HWN + n0 + n];
  }
  __syncthreads();
  unsigned short* xo = xT + (size_t)b * HWN * CC;
#pragma unroll
  for (int i = 0; i < 4; i++) {
    int e = tid + i * 256;
    int c2 = e & 15, n = e >> 4;
    unsigned vv = (unsigned)f2b(ts[2 * c2][n]) | ((unsigned)f2b(ts[2 * c2 + 1][n]) << 16);
    *(unsigned*)&xo[(size_t)(n0 + n) * CC + c0 + 2 * c2] = vv;
  }
}

// ---------------------------------------------------------------------------
// g1: A16[b][k][n] = bf16( sum_c cls[k][c]*x[c][n] )  via MFMA
// block: 128 n x 160 k; wave w covers n [32w,32w+31], 10 m-tiles
// ---------------------------------------------------------------------------
__global__ __launch_bounds__(256) void g1_mfma(const unsigned short* __restrict__ xT,
                                               const unsigned short* __restrict__ cls16,
                                               unsigned short* __restrict__ A16) {
  const int n0 = blockIdx.x * 128, b = blockIdx.y;
  const int tid = threadIdx.x, w = tid >> 6, L = tid & 63;
  const int q = L >> 4, m16 = L & 15;
  __shared__ __align__(16) unsigned short xs[128 * 40];
  f4v zf = {0.f, 0.f, 0.f, 0.f};
  f4v acc[10][2];
#pragma unroll
  for (int mt = 0; mt < 10; mt++) { acc[mt][0] = zf; acc[mt][1] = zf; }
  const unsigned short* xTb = xT + (size_t)(b * HWN + n0) * CC;
  for (int c0 = 0; c0 < CC; c0 += 32) {
    __syncthreads();
#pragma unroll
    for (int i = 0; i < 2; i++) {
      int e = tid + i * 256;
      int c8 = e & 3, n = e >> 2;
      bf8v t = *(const bf8v*)&xTb[(size_t)n * CC + c0 + 8 * c8];
      *(bf8v*)&xs[n * 40 + 8 * c8] = t;
    }
    __syncthreads();
    bf8v bfrag0 = *(const bf8v*)&xs[(32 * w + m16) * 40 + 8 * q];
    bf8v bfrag1 = *(const bf8v*)&xs[(32 * w + 16 + m16) * 40 + 8 * q];
#pragma unroll
    for (int mt = 0; mt < 10; mt++) {
      bf8v afrag = *(const bf8v*)&cls16[(size_t)(16 * mt + m16) * CC + c0 + 8 * q];
      acc[mt][0] = __builtin_amdgcn_mfma_f32_16x16x32_bf16(afrag, bfrag0, acc[mt][0], 0, 0, 0);
      acc[mt][1] = __builtin_amdgcn_mfma_f32_16x16x32_bf16(afrag, bfrag1, acc[mt][1], 0, 0, 0);
    }
  }
#pragma unroll
  for (int mt = 0; mt < 10; mt++)
#pragma unroll
    for (int r = 0; r < 4; r++) {
      int k = 16 * mt + 4 * q + r;
      if (k < KK) {
        size_t row = (size_t)(b * KK + k) * HWN + n0 + 32 * w;
        A16[row + m16] = f2b(acc[mt][0][r]);
        A16[row + 16 + m16] = f2b(acc[mt][1][r]);
      }
    }
}

// ---------------------------------------------------------------------------
// g2a: per-(b,k) rowmax, rowsum over n (from bf16 A)
// ---------------------------------------------------------------------------
__global__ __launch_bounds__(256) void g2a_rowstats(const unsigned short* __restrict__ A16,
                                                    float* __restrict__ rowmax,
                                                    float* __restrict__ rowsum) {
  const int bk = blockIdx.x;
  const bf8v* row = (const bf8v*)(A16 + (size_t)bk * HWN);
  __shared__ float red[8];
  const int tid = threadIdx.x, lane = tid & 63, w = tid >> 6;
  float m = -1e30f;
  for (int i = tid; i < HWN / 8; i += 256) {
    bf8v u = row[i];
#pragma unroll
    for (int j = 0; j < 8; j++) m = fmaxf(m, b2fs(u[j]));
  }
#pragma unroll
  for (int o = 32; o > 0; o >>= 1) m = fmaxf(m, __shfl_down(m, o, 64));
  if (lane == 0) red[w] = m;
  __syncthreads();
  if (tid == 0) red[4] = fmaxf(fmaxf(red[0], red[1]), fmaxf(red[2], red[3]));
  __syncthreads();
  const float mm = red[4];
  float s = 0.f;
  for (int i = tid; i < HWN / 8; i += 256) {
    bf8v u = row[i];
#pragma unroll
    for (int j = 0; j < 8; j++) s += __expf(b2fs(u[j]) - mm);
  }
#pragma unroll
  for (int o = 32; o > 0; o >>= 1) s += __shfl_down(s, o, 64);
  if (lane == 0) red[w] = s;
  __syncthreads();
  if (tid == 0) {
    rowmax[bk] = mm;
    rowsum[bk] = red[0] + red[1] + red[2] + red[3];
  }
}

// ---------------------------------------------------------------------------
// g2b: v[n] = exp(-colmax)/colsum (per b,n over k)
// ---------------------------------------------------------------------------
__global__ __launch_bounds__(256) void g2b_colstats(const unsigned short* __restrict__ A16,
                                                    float* __restrict__ vvec) {
  const int b = blockIdx.y;
  const int n = blockIdx.x * 256 + threadIdx.x;
  const unsigned short* Ab = A16 + (size_t)b * KK * HWN + n;
  float m = -1e30f;
  for (int k = 0; k < KK; k++) m = fmaxf(m, b2f(Ab[(size_t)k * HWN]));
  float s = 0.f;
  for (int k = 0; k < KK; k++) s += __expf(b2f(Ab[(size_t)k * HWN]) - m);
  vvec[b * HWN + n] = __expf(-m) / s;
}

// ---------------------------------------------------------------------------
// g3: Scp[b][seg][k][c] = sum_{n in seg} exp(A-rowmax)*x[c][n]  via MFMA
// block tile [160 k x 128 c]; wave: 5 m-tiles (kgrp) x 4 col-chunks (cgrp)
// E staged+exp'd in LDS per 32-n chunk; x frags straight from fp32 global.
// ---------------------------------------------------------------------------
__global__ __launch_bounds__(256) void g3_mfma(const float* __restrict__ x,
                                               const unsigned short* __restrict__ A16,
                                               const float* __restrict__ rowmax,
                                               float* __restrict__ Scp) {
  const int cblk = blockIdx.x, seg = blockIdx.y, b = blockIdx.z;
  const int tid = threadIdx.x, w = tid >> 6, L = tid & 63;
  const int q = L >> 4, m16 = L & 15;
  const int kgrp = w & 1, cgrp = w >> 1;
  __shared__ __align__(16) unsigned short Es[KP * 40];
  __shared__ float Rm[KP];
  if (tid < KP) Rm[tid] = (tid < KK) ? rowmax[b * KK + tid] : 0.f;
  f4v zf = {0.f, 0.f, 0.f, 0.f};
  f4v acc[5][4];
#pragma unroll
  for (int mt = 0; mt < 5; mt++)
#pragma unroll
    for (int cc = 0; cc < 4; cc++) acc[mt][cc] = zf;
  const float* xb = x + (size_t)b * CC * HWN;
  const int nend = (seg + 1) * SEGN;
  for (int nc0 = seg * SEGN; nc0 < nend; nc0 += 32) {
    __syncthreads();
#pragma unroll
    for (int i = 0; i < 3; i++) {
      int e = tid + i * 256;
      if (e < 640) {
        int n8 = e & 3, k = e >> 2;
        bf8v o;
        if (k < KK) {
          bf8v a = *(const bf8v*)&A16[(size_t)(b * KK + k) * HWN + nc0 + 8 * n8];
          float rm = Rm[k];
#pragma unroll
          for (int j = 0; j < 8; j++) o[j] = (short)f2b(__expf(b2fs(a[j]) - rm));
        } else {
#pragma unroll
          for (int j = 0; j < 8; j++) o[j] = 0;
        }
        *(bf8v*)&Es[k * 40 + 8 * n8] = o;
      }
    }
    __syncthreads();
    bf8v afrag[5];
#pragma unroll
    for (int mt = 0; mt < 5; mt++)
      afrag[mt] = *(const bf8v*)&Es[(80 * kgrp + 16 * mt + m16) * 40 + 8 * q];
#pragma unroll
    for (int cc = 0; cc < 4; cc++) {
      int c = cblk * 128 + 64 * cgrp + 16 * cc + m16;
      const float* xp = &xb[(size_t)c * HWN + nc0 + 8 * q];
      float4 x0 = *(const float4*)xp;
      float4 x1 = *(const float4*)(xp + 4);
      bf8v bf;
      bf[0] = (short)f2b(x0.x); bf[1] = (short)f2b(x0.y);
      bf[2] = (short)f2b(x0.z); bf[3] = (short)f2b(x0.w);
      bf[4] = (short)f2b(x1.x); bf[5] = (short)f2b(x1.y);
      bf[6] = (short)f2b(x1.z); bf[7] = (short)f2b(x1.w);
#pragma unroll
      for (int mt = 0; mt < 5; mt++)
        acc[mt][cc] = __builtin_amdgcn_mfma_f32_16x16x32_bf16(afrag[mt], bf, acc[mt][cc], 0, 0, 0);
    }
  }
#pragma unroll
  for (int mt = 0; mt < 5; mt++)
#pragma unroll
    for (int cc = 0; cc < 4; cc++)
#pragma unroll
      for (int r = 0; r < 4; r++) {
        int k = 80 * kgrp + 16 * mt + 4 * q + r;
        if (k < KK) {
          int c = cblk * 128 + 64 * cgrp + 16 * cc + m16;
          Scp[(((size_t)(b * NSEG + seg)) * KK + k) * CC + c] = acc[mt][cc][r];
        }
      }
}

// ---------------------------------------------------------------------------
// g5: Sc = (sum_seg Scp)/rowsum
// ---------------------------------------------------------------------------
__global__ __launch_bounds__(256) void g5_reduce(const float* __restrict__ Scp,
                                                 const float* __restrict__ rowsum,
                                                 float* __restrict__ Sc) {
  const int bk = blockIdx.x;
  const int b = bk / KK, k = bk % KK;
  const float inv = 1.0f / rowsum[bk];
  for (int c = threadIdx.x; c < CC; c += 256) {
    float s = 0.f;
    for (int g = 0; g < NSEG; g++)
      s += Scp[(((size_t)(b * NSEG + g)) * KK + k) * CC + c];
    Sc[(size_t)bk * CC + c] = s * inv;
  }
}

// ---------------------------------------------------------------------------
// g4b: CWf[k][j] = sum_c cls[k][c]*Wf[j][c]
// ---------------------------------------------------------------------------
__global__ __launch_bounds__(256) void g4b_cwf(const float* __restrict__ cls,
                                               const float* __restrict__ Wf,
                                               float* __restrict__ CWf) {
  const int k = blockIdx.y;
  const int w = threadIdx.x >> 6, lane = threadIdx.x & 63;
  const int j0 = (blockIdx.x * 4 + w) * 4;
  const float4* arow = (const float4*)(cls + (size_t)k * CC);
  float4 a0 = arow[lane], a1 = arow[64 + lane];
#pragma unroll
  for (int jj = 0; jj < 4; jj++) {
    const float4* brow = (const float4*)(Wf + (size_t)(j0 + jj) * CC);
    float4 b0 = brow[lane], b1 = brow[64 + lane];
    float d = a0.x * b0.x + a0.y * b0.y + a0.z * b0.z + a0.w * b0.w +
              a1.x * b1.x + a1.y * b1.y + a1.z * b1.z + a1.w * b1.w;
#pragma unroll
    for (int o = 32; o > 0; o >>= 1) d += __shfl_down(d, o, 64);
    if (lane == 0) CWf[(size_t)k * CC + j0 + jj] = d;
  }
}

// ---------------------------------------------------------------------------
// g4a: AC[bk][j] = cls[k][j] + sum_c Sc[bk][c]*Wc[j][c]; also writes AC16
// ---------------------------------------------------------------------------
__global__ __launch_bounds__(256) void g4a_ac(const float* __restrict__ Sc,
                                              const float* __restrict__ Wc,
                                              const float* __restrict__ cls,
                                              float* __restrict__ AC,
                                              unsigned short* __restrict__ AC16) {
  const int bk = blockIdx.y;
  const int b = bk / KK, k = bk % KK;
  const int w = threadIdx.x >> 6, lane = threadIdx.x & 63;
  const int j0 = (blockIdx.x * 4 + w) * 4;
  const float4* arow = (const float4*)(Sc + (size_t)bk * CC);
  float4 a0 = arow[lane], a1 = arow[64 + lane];
#pragma unroll
  for (int jj = 0; jj < 4; jj++) {
    const float4* brow = (const float4*)(Wc + (size_t)(j0 + jj) * CC);
    float4 b0 = brow[lane], b1 = brow[64 + lane];
    float d = a0.x * b0.x + a0.y * b0.y + a0.z * b0.z + a0.w * b0.w +
              a1.x * b1.x + a1.y * b1.y + a1.z * b1.z + a1.w * b1.w;
#pragma unroll
    for (int o = 32; o > 0; o >>= 1) d += __shfl_down(d, o, 64);
    if (lane == 0) {
      float val = cls[k * CC + j0 + jj] + d;
      AC[(size_t)bk * CC + j0 + jj] = val;
      AC16[((size_t)b * KP + k) * CC + j0 + jj] = f2b(val);
    }
  }
}

// ---------------------------------------------------------------------------
// g4c: MT16[b][k2][k1] = bf16( exp(rowmax[k1]) * sum_c CWf[k1][c]*AC[b,k2][c] )
// ---------------------------------------------------------------------------
__global__ __launch_bounds__(256) void g4c_m(const float* __restrict__ CWf,
                                             const float* __restrict__ AC,
                                             const float* __restrict__ rowmax,
                                             unsigned short* __restrict__ MT16) {
  const int k1 = blockIdx.y, b = blockIdx.z;
  const int w = threadIdx.x >> 6, lane = threadIdx.x & 63;
  const int k20 = (blockIdx.x * 4 + w) * 4;
  const float4* arow = (const float4*)(CWf + (size_t)k1 * CC);
  float4 a0 = arow[lane], a1 = arow[64 + lane];
  const float u = __expf(rowmax[b * KK + k1]);
#pragma unroll
  for (int jj = 0; jj < 4; jj++) {
    int k2 = k20 + jj;
    if (k2 >= KK) break;
    const float4* brow = (const float4*)(AC + (size_t)(b * KK + k2) * CC);
    float4 b0 = brow[lane], b1 = brow[64 + lane];
    float d = a0.x * b0.x + a0.y * b0.y + a0.z * b0.z + a0.w * b0.w +
              a1.x * b1.x + a1.y * b1.y + a1.z * b1.z + a1.w * b1.w;
#pragma unroll
    for (int o = 32; o > 0; o >>= 1) d += __shfl_down(d, o, 64);
    if (lane == 0) MT16[((size_t)b * KP + k2) * KP + k1] = f2b(d * u);
  }
}

// ---------------------------------------------------------------------------
// g6: masks[k][n] = v[n]*(sum_k' MT'[k][k']*E''[k'][n]) + sum_c AC[k][c]*x[c][n]
//     then LayerNorm over k, write out[b][k][n].  All-MFMA.
// ---------------------------------------------------------------------------
__global__ __launch_bounds__(256) void g6_mfma(
    const unsigned short* __restrict__ xT, const unsigned short* __restrict__ A16,
    const float* __restrict__ rowmax, const float* __restrict__ vvec,
    const unsigned short* __restrict__ AC16, const unsigned short* __restrict__ MT16,
    const float* __restrict__ gamma, const float* __restrict__ beta,
    float* __restrict__ out) {
  const int n0 = blockIdx.x * 128, b = blockIdx.y;
  const int tid = threadIdx.x, w = tid >> 6, L = tid & 63;
  const int q = L >> 4, m16 = L & 15;
  __shared__ __align__(16) unsigned short sbuf[128 * 40];
  __shared__ float gbuf[KP], bbuf[KP], Rm[KP];
  if (tid < KP) {
    gbuf[tid] = (tid < KK) ? gamma[tid] : 0.f;
    bbuf[tid] = (tid < KK) ? beta[tid] : 0.f;
    Rm[tid] = (tid < KK) ? rowmax[b * KK + tid] : 0.f;
  }
  f4v zf = {0.f, 0.f, 0.f, 0.f};
  f4v acc[10][2];
#pragma unroll
  for (int mt = 0; mt < 10; mt++) { acc[mt][0] = zf; acc[mt][1] = zf; }

  // ---- part 2: acc = sum_k' MT'[k][k'] * E''[k'][n] ----
  const unsigned short* MTb = MT16 + (size_t)b * KP * KP;
  for (int kc0 = 0; kc0 < KP; kc0 += 32) {
    __syncthreads();
#pragma unroll
    for (int i = 0; i < 2; i++) {
      int e = tid + i * 256;
      int n8 = e & 15, kr = e >> 4;
      int kp = kc0 + kr;
      if (kp < KK) {
        bf8v a = *(const bf8v*)&A16[(size_t)(b * KK + kp) * HWN + n0 + 8 * n8];
        float rm = Rm[kp];
#pragma unroll
        for (int jj = 0; jj < 8; jj++) {
          int j = (jj + n8) & 7;  // stagger to spread LDS banks
          sbuf[(8 * n8 + j) * 40 + kr] = f2b(__expf(b2fs(a[j]) - rm));
        }
      } else {
#pragma unroll
        for (int jj = 0; jj < 8; jj++) {
          int j = (jj + n8) & 7;
          sbuf[(8 * n8 + j) * 40 + kr] = 0;
        }
      }
    }
    __syncthreads();
    bf8v bfrag0 = *(const bf8v*)&sbuf[(32 * w + m16) * 40 + 8 * q];
    bf8v bfrag1 = *(const bf8v*)&sbuf[(32 * w + 16 + m16) * 40 + 8 * q];
#pragma unroll
    for (int mt = 0; mt < 10; mt++) {
      bf8v afrag = *(const bf8v*)&MTb[(size_t)(16 * mt + m16) * KP + kc0 + 8 * q];
      acc[mt][0] = __builtin_amdgcn_mfma_f32_16x16x32_bf16(afrag, bfrag0, acc[mt][0], 0, 0, 0);
      acc[mt][1] = __builtin_amdgcn_mfma_f32_16x16x32_bf16(afrag, bfrag1, acc[mt][1], 0, 0, 0);
    }
  }
  // scale part2 by v[n]
  const float v0 = vvec[b * HWN + n0 + 32 * w + m16];
  const float v1 = vvec[b * HWN + n0 + 32 * w + 16 + m16];
#pragma unroll
  for (int mt = 0; mt < 10; mt++)
#pragma unroll
    for (int r = 0; r < 4; r++) {
      acc[mt][0][r] *= v0;
      acc[mt][1][r] *= v1;
    }

  // ---- part 1: acc += sum_c AC[k][c]*x[c][n] ----
  const unsigned short* xTb = xT + (size_t)(b * HWN + n0) * CC;
  const unsigned short* ACb = AC16 + (size_t)b * KP * CC;
  for (int c0 = 0; c0 < CC; c0 += 32) {
    __syncthreads();
#pragma unroll
    for (int i = 0; i < 2; i++) {
      int e = tid + i * 256;
      int c8 = e & 3, n = e >> 2;
      bf8v t = *(const bf8v*)&xTb[(size_t)n * CC + c0 + 8 * c8];
      *(bf8v*)&sbuf[n * 40 + 8 * c8] = t;
    }
    __syncthreads();
    bf8v bfrag0 = *(const bf8v*)&sbuf[(32 * w + m16) * 40 + 8 * q];
    bf8v bfrag1 = *(const bf8v*)&sbuf[(32 * w + 16 + m16) * 40 + 8 * q];
#pragma unroll
    for (int mt = 0; mt < 10; mt++) {
      bf8v afrag = *(const bf8v*)&ACb[(size_t)(16 * mt + m16) * CC + c0 + 8 * q];
      acc[mt][0] = __builtin_amdgcn_mfma_f32_16x16x32_bf16(afrag, bfrag0, acc[mt][0], 0, 0, 0);
      acc[mt][1] = __builtin_amdgcn_mfma_f32_16x16x32_bf16(afrag, bfrag1, acc[mt][1], 0, 0, 0);
    }
  }

  // ---- LayerNorm over k per n (k rows padded >=150 are exactly zero) ----
  float s1[2] = {0.f, 0.f}, s2[2] = {0.f, 0.f};
#pragma unroll
  for (int mt = 0; mt < 10; mt++)
#pragma unroll
    for (int r = 0; r < 4; r++) {
#pragma unroll
      for (int nc = 0; nc < 2; nc++) {
        float a = acc[mt][nc][r];
        s1[nc] += a;
        s2[nc] += a * a;
      }
    }
#pragma unroll
  for (int nc = 0; nc < 2; nc++) {
    s1[nc] += __shfl_xor(s1[nc], 16, 64);
    s1[nc] += __shfl_xor(s1[nc], 32, 64);
    s2[nc] += __shfl_xor(s2[nc], 16, 64);
    s2[nc] += __shfl_xor(s2[nc], 32, 64);
  }
  float mu[2], inv[2];
#pragma unroll
  for (int nc = 0; nc < 2; nc++) {
    mu[nc] = s1[nc] * (1.0f / KK);
    float var = s2[nc] * (1.0f / KK) - mu[nc] * mu[nc];
    inv[nc] = rsqrtf(var + 1e-5f);
  }
#pragma unroll
  for (int mt = 0; mt < 10; mt++)
#pragma unroll
    for (int r = 0; r < 4; r++) {
      int k = 16 * mt + 4 * q + r;
      if (k < KK) {
        float g = gbuf[k], be = bbuf[k];
        size_t row = (size_t)(b * KK + k) * HWN + n0 + 32 * w;
        out[row + m16] = (acc[mt][0][r] - mu[0]) * inv[0] * g + be;
        out[row + 16 + m16] = (acc[mt][1][r] - mu[1]) * inv[1] * g + be;
      }
    }
}

// ---------------------------------------------------------------------------
extern "C" void kernel_launch(void* const* d_in, const int* in_sizes, int n_in,
                              void* d_out, int out_size, void* d_ws, size_t ws_size,
                              hipStream_t stream) {
  const float* x = (const float*)d_in[0];
  const float* cls = (const float*)d_in[1];
  const float* Wc = (const float*)d_in[2];
  const float* Wf = (const float*)d_in[3];
  const float* gam = (const float*)d_in[4];
  const float* bet = (const float*)d_in[5];
  float* out = (float*)d_out;

  char* p = (char*)d_ws;
  auto alloc = [&](size_t bytes) {
    char* r = p;
    p += (bytes + 255) & ~(size_t)255;
    return r;
  };
  unsigned short* xT16 = (unsigned short*)alloc((size_t)BB * HWN * CC * 2);
  unsigned short* A16 = (unsigned short*)alloc((size_t)(BB * KK + 16) * HWN * 2);
  float* Scp = (float*)alloc((size_t)BB * NSEG * KK * CC * 4);
  float* Sc = (float*)alloc((size_t)BB * KK * CC * 4);
  float* AC = (float*)alloc((size_t)BB * KK * CC * 4);
  unsigned short* AC16 = (unsigned short*)alloc((size_t)BB * KP * CC * 2);
  float* CWf = (float*)alloc((size_t)KK * CC * 4);
  unsigned short* cls16 = (unsigned short*)alloc((size_t)KP * CC * 2);
  unsigned short* MT16 = (unsigned short*)alloc((size_t)BB * KP * KP * 2);
  float* rowmax = (float*)alloc(BB * KK * 4);
  float* rowsum = (float*)alloc(BB * KK * 4);
  float* vvec = (float*)alloc((size_t)BB * HWN * 4);

  t0_prep<<<dim3((BB * KP * KP + 255) / 256), 256, 0, stream>>>(cls, cls16, MT16, AC16);
  t1_transpose<<<dim3(HWN / 64, CC / 32, BB), 256, 0, stream>>>(x, xT16);
  g1_mfma<<<dim3(HWN / 128, BB), 256, 0, stream>>>(xT16, cls16, A16);
  g2a_rowstats<<<dim3(BB * KK), 256, 0, stream>>>(A16, rowmax, rowsum);
  g2b_colstats<<<dim3(HWN / 256, BB), 256, 0, stream>>>(A16, vvec);
  g3_mfma<<<dim3(CC / 128, NSEG, BB), 256, 0, stream>>>(x, A16, rowmax, Scp);
  g5_reduce<<<dim3(BB * KK), 256, 0, stream>>>(Scp, rowsum, Sc);
  g4b_cwf<<<dim3(CC / 16, KK), 256, 0, stream>>>(cls, Wf, CWf);
  g4a_ac<<<dim3(CC / 16, BB * KK), 256, 0, stream>>>(Sc, Wc, cls, AC, AC16);
  g4c_m<<<dim3(10, KK, BB), 256, 0, stream>>>(CWf, AC, rowmax, MT16);
  g6_mfma<<<dim3(HWN / 128, BB), 256, 0, stream>>>(xT16, A16, rowmax, vvec, AC16, MT16,
                                                   gam, bet, out);
}

// Round 3
// 929.572 us; speedup vs baseline: 2.9047x; 1.1871x over previous
//
#include <hip/hip_runtime.h>
#include <math.h>

#define BB 8
#define CC 512
#define HWN 16384
#define KK 150
#define KP 160
#define NSEG 32
#define SEGN (HWN / NSEG)  // 512

typedef short bf8v __attribute__((ext_vector_type(8)));
typedef float f4v __attribute__((ext_vector_type(4)));

static __device__ inline unsigned short f2b(float f) {
  unsigned u = __float_as_uint(f);
  u += 0x7fffu + ((u >> 16) & 1u);
  return (unsigned short)(u >> 16);
}
static __device__ inline float b2f(unsigned short s) {
  return __uint_as_float(((unsigned)s) << 16);
}
static __device__ inline float b2fs(short s) { return b2f((unsigned short)s); }

// ---------------------------------------------------------------------------
// t0: build cls16 [160][512] (rows >=150 zero), zero MT16, zero AC16 pad rows
// ---------------------------------------------------------------------------
__global__ __launch_bounds__(256) void t0_prep(const float* __restrict__ cls,
                                               unsigned short* __restrict__ cls16,
                                               unsigned short* __restrict__ MT16,
                                               unsigned short* __restrict__ AC16) {
  int i = blockIdx.x * 256 + threadIdx.x;
  if (i < KP * CC) {
    int k = i >> 9, c = i & 511;
    cls16[i] = (k < KK) ? f2b(cls[k * CC + c]) : 0;
  }
  if (i < BB * KP * KP) MT16[i] = 0;
  if (i < BB * (KP - KK) * CC) {
    int b = i / ((KP - KK) * CC);
    int r = i % ((KP - KK) * CC);
    int k = KK + (r >> 9);
    int c = r & 511;
    AC16[((size_t)b * KP + k) * CC + c] = 0;
  }
}

// ---------------------------------------------------------------------------
// t1: x [b][c][n] fp32 -> xT16 [b][n][c] bf16  (LDS tile transpose)
// ---------------------------------------------------------------------------
__global__ __launch_bounds__(256) void t1_transpose(const float* __restrict__ x,
                                                    unsigned short* __restrict__ xT) {
  __shared__ float ts[32][65];
  const int n0 = blockIdx.x * 64, c0 = blockIdx.y * 32, b = blockIdx.z;
  const int tid = threadIdx.x;
  const float* xb = x + (size_t)b * CC * HWN;
#pragma unroll
  for (int i = 0; i < 8; i++) {
    int e = tid + i * 256;
    int n = e & 63, c = e >> 6;
    ts[c][n] = xb[(size_t)(c0 + c) * HWN + n0 + n];
  }
  __syncthreads();
  unsigned short* xo = xT + (size_t)b * HWN * CC;
#pragma unroll
  for (int i = 0; i < 4; i++) {
    int e = tid + i * 256;
    int c2 = e & 15, n = e >> 4;
    unsigned vv = (unsigned)f2b(ts[2 * c2][n]) | ((unsigned)f2b(ts[2 * c2 + 1][n]) << 16);
    *(unsigned*)&xo[(size_t)(n0 + n) * CC + c0 + 2 * c2] = vv;
  }
}

// ---------------------------------------------------------------------------
// g1: A16[b][k][n] = bf16( sum_c cls[k][c]*x[c][n] ) via MFMA, no LDS/barriers.
// Also fuses column softmax stats -> vvec[n] = exp(-colmax)/colsum (fp32 acc).
// ---------------------------------------------------------------------------
__global__ __launch_bounds__(256) void g1_mfma(const unsigned short* __restrict__ xT,
                                               const unsigned short* __restrict__ cls16,
                                               unsigned short* __restrict__ A16,
                                               float* __restrict__ vvec) {
  const int n0 = blockIdx.x * 128, b = blockIdx.y;
  const int tid = threadIdx.x, w = tid >> 6, L = tid & 63;
  const int q = L >> 4, m16 = L & 15;
  f4v zf = {0.f, 0.f, 0.f, 0.f};
  f4v acc[10][2];
#pragma unroll
  for (int mt = 0; mt < 10; mt++) { acc[mt][0] = zf; acc[mt][1] = zf; }
  const unsigned short* xr0 = xT + ((size_t)(b * HWN + n0 + 32 * w + m16)) * CC + 8 * q;
  const unsigned short* xr1 = xr0 + 16 * CC;
  const unsigned short* cb = cls16 + (size_t)m16 * CC + 8 * q;
#pragma unroll 2
  for (int c0 = 0; c0 < CC; c0 += 32) {
    bf8v b0 = *(const bf8v*)(xr0 + c0);
    bf8v b1 = *(const bf8v*)(xr1 + c0);
#pragma unroll
    for (int mt = 0; mt < 10; mt++) {
      bf8v a = *(const bf8v*)(cb + (size_t)(16 * mt) * CC + c0);
      acc[mt][0] = __builtin_amdgcn_mfma_f32_16x16x32_bf16(a, b0, acc[mt][0], 0, 0, 0);
      acc[mt][1] = __builtin_amdgcn_mfma_f32_16x16x32_bf16(a, b1, acc[mt][1], 0, 0, 0);
    }
  }
  // store A16
#pragma unroll
  for (int mt = 0; mt < 10; mt++)
#pragma unroll
    for (int r = 0; r < 4; r++) {
      int k = 16 * mt + 4 * q + r;
      if (k < KK) {
        size_t row = ((size_t)(b * KK + k)) * HWN + n0 + 32 * w;
        A16[row + m16] = f2b(acc[mt][0][r]);
        A16[row + 16 + m16] = f2b(acc[mt][1][r]);
      }
    }
  // fused column stats (over k) from fp32 acc
  float cm[2] = {-1e30f, -1e30f}, cs[2] = {0.f, 0.f};
  const int kq = 4 * q;
#pragma unroll
  for (int mt = 0; mt < 10; mt++)
#pragma unroll
    for (int r = 0; r < 4; r++) {
      bool valid = (16 * mt + kq + r) < KK;
#pragma unroll
      for (int nc = 0; nc < 2; nc++) {
        float a = valid ? acc[mt][nc][r] : -1e30f;
        cm[nc] = fmaxf(cm[nc], a);
      }
    }
#pragma unroll
  for (int mt = 0; mt < 10; mt++)
#pragma unroll
    for (int r = 0; r < 4; r++) {
      bool valid = (16 * mt + kq + r) < KK;
#pragma unroll
      for (int nc = 0; nc < 2; nc++)
        if (valid) cs[nc] += __expf(acc[mt][nc][r] - cm[nc]);
    }
#pragma unroll
  for (int off = 16; off < 64; off <<= 1) {
#pragma unroll
    for (int nc = 0; nc < 2; nc++) {
      float m2 = __shfl_xor(cm[nc], off, 64);
      float s2 = __shfl_xor(cs[nc], off, 64);
      float mn = fmaxf(cm[nc], m2);
      cs[nc] = cs[nc] * __expf(cm[nc] - mn) + s2 * __expf(m2 - mn);
      cm[nc] = mn;
    }
  }
  if (q == 0) {
#pragma unroll
    for (int nc = 0; nc < 2; nc++)
      vvec[b * HWN + n0 + 32 * w + 16 * nc + m16] = __expf(-cm[nc]) / cs[nc];
  }
}

// ---------------------------------------------------------------------------
// g2a: per-(b,k) rowmax, rowsum over n (from bf16 A)
// ---------------------------------------------------------------------------
__global__ __launch_bounds__(256) void g2a_rowstats(const unsigned short* __restrict__ A16,
                                                    float* __restrict__ rowmax,
                                                    float* __restrict__ rowsum) {
  const int bk = blockIdx.x;
  const bf8v* row = (const bf8v*)(A16 + (size_t)bk * HWN);
  __shared__ float red[8];
  const int tid = threadIdx.x, lane = tid & 63, w = tid >> 6;
  float m = -1e30f;
  for (int i = tid; i < HWN / 8; i += 256) {
    bf8v u = row[i];
#pragma unroll
    for (int j = 0; j < 8; j++) m = fmaxf(m, b2fs(u[j]));
  }
#pragma unroll
  for (int o = 32; o > 0; o >>= 1) m = fmaxf(m, __shfl_down(m, o, 64));
  if (lane == 0) red[w] = m;
  __syncthreads();
  if (tid == 0) red[4] = fmaxf(fmaxf(red[0], red[1]), fmaxf(red[2], red[3]));
  __syncthreads();
  const float mm = red[4];
  float s = 0.f;
  for (int i = tid; i < HWN / 8; i += 256) {
    bf8v u = row[i];
#pragma unroll
    for (int j = 0; j < 8; j++) s += __expf(b2fs(u[j]) - mm);
  }
#pragma unroll
  for (int o = 32; o > 0; o >>= 1) s += __shfl_down(s, o, 64);
  if (lane == 0) red[w] = s;
  __syncthreads();
  if (tid == 0) {
    rowmax[bk] = mm;
    rowsum[bk] = red[0] + red[1] + red[2] + red[3];
  }
}

// ---------------------------------------------------------------------------
// e1: E16[b][kp][n] = exp(A-rowmax) (row-major, KP rows, pad=0) and
//     ET16[b][n][kp] (transposed via LDS).  Tile: 32 k x 64 n.
// ---------------------------------------------------------------------------
__global__ __launch_bounds__(256) void e1_exp(const unsigned short* __restrict__ A16,
                                              const float* __restrict__ rowmax,
                                              unsigned short* __restrict__ E16,
                                              unsigned short* __restrict__ ET16) {
  const int n0 = blockIdx.x * 64, k0 = blockIdx.y * 32, b = blockIdx.z;
  const int tid = threadIdx.x;
  __shared__ unsigned short ls[64 * 33];
  const int kr = tid >> 3, n8 = tid & 7;
  const int k = k0 + kr;
  bf8v e;
  if (k < KK) {
    float rm = rowmax[b * KK + k];
    bf8v a = *(const bf8v*)&A16[((size_t)(b * KK + k)) * HWN + n0 + 8 * n8];
#pragma unroll
    for (int j = 0; j < 8; j++) e[j] = (short)f2b(__expf(b2fs(a[j]) - rm));
  } else {
#pragma unroll
    for (int j = 0; j < 8; j++) e[j] = 0;
  }
  *(bf8v*)&E16[((size_t)(b * KP + k)) * HWN + n0 + 8 * n8] = e;
#pragma unroll
  for (int j = 0; j < 8; j++) ls[(8 * n8 + j) * 33 + kr] = (unsigned short)e[j];
  __syncthreads();
  const int n = tid >> 2, k8 = tid & 3;
  bf8v o;
#pragma unroll
  for (int j = 0; j < 8; j++) o[j] = (short)ls[n * 33 + 8 * k8 + j];
  *(bf8v*)&ET16[((size_t)(b * HWN + n0 + n)) * KP + k0 + 8 * k8] = o;
}

// ---------------------------------------------------------------------------
// g3: Scp[b][seg][k][c] = sum_{n in seg} E[k][n]*x[c][n]  via MFMA, no LDS.
// ---------------------------------------------------------------------------
__global__ __launch_bounds__(256) void g3_mfma(const float* __restrict__ x,
                                               const unsigned short* __restrict__ E16,
                                               float* __restrict__ Scp) {
  const int cblk = blockIdx.x, seg = blockIdx.y, b = blockIdx.z;
  const int tid = threadIdx.x, w = tid >> 6, L = tid & 63;
  const int q = L >> 4, m16 = L & 15;
  const int kgrp = w & 1, cgrp = w >> 1;
  f4v zf = {0.f, 0.f, 0.f, 0.f};
  f4v acc[5][4];
#pragma unroll
  for (int mt = 0; mt < 5; mt++)
#pragma unroll
    for (int cc = 0; cc < 4; cc++) acc[mt][cc] = zf;
  const unsigned short* eb = E16 + ((size_t)(b * KP + 80 * kgrp + m16)) * HWN + 8 * q;
  const float* xb = x + (size_t)b * CC * HWN +
                    (size_t)(cblk * 128 + 64 * cgrp + m16) * HWN + 8 * q;
  const int ns0 = seg * SEGN;
#pragma unroll 2
  for (int nc0 = ns0; nc0 < ns0 + SEGN; nc0 += 32) {
    bf8v af[5];
#pragma unroll
    for (int mt = 0; mt < 5; mt++)
      af[mt] = *(const bf8v*)(eb + (size_t)(16 * mt) * HWN + nc0);
#pragma unroll
    for (int cc = 0; cc < 4; cc++) {
      const float* xp = xb + (size_t)(16 * cc) * HWN + nc0;
      float4 x0 = *(const float4*)xp;
      float4 x1 = *(const float4*)(xp + 4);
      bf8v bf;
      bf[0] = (short)f2b(x0.x); bf[1] = (short)f2b(x0.y);
      bf[2] = (short)f2b(x0.z); bf[3] = (short)f2b(x0.w);
      bf[4] = (short)f2b(x1.x); bf[5] = (short)f2b(x1.y);
      bf[6] = (short)f2b(x1.z); bf[7] = (short)f2b(x1.w);
#pragma unroll
      for (int mt = 0; mt < 5; mt++)
        acc[mt][cc] = __builtin_amdgcn_mfma_f32_16x16x32_bf16(af[mt], bf, acc[mt][cc], 0, 0, 0);
    }
  }
#pragma unroll
  for (int mt = 0; mt < 5; mt++)
#pragma unroll
    for (int cc = 0; cc < 4; cc++)
#pragma unroll
      for (int r = 0; r < 4; r++) {
        int k = 80 * kgrp + 16 * mt + 4 * q + r;
        if (k < KK) {
          int c = cblk * 128 + 64 * cgrp + 16 * cc + m16;
          Scp[(((size_t)(b * NSEG + seg)) * KK + k) * CC + c] = acc[mt][cc][r];
        }
      }
}

// ---------------------------------------------------------------------------
// g5: Sc = (sum_seg Scp)/rowsum
// ---------------------------------------------------------------------------
__global__ __launch_bounds__(256) void g5_reduce(const float* __restrict__ Scp,
                                                 const float* __restrict__ rowsum,
                                                 float* __restrict__ Sc) {
  const int bk = blockIdx.x;
  const int b = bk / KK, k = bk % KK;
  const float inv = 1.0f / rowsum[bk];
  for (int c = threadIdx.x; c < CC; c += 256) {
    float s = 0.f;
    for (int g = 0; g < NSEG; g++)
      s += Scp[(((size_t)(b * NSEG + g)) * KK + k) * CC + c];
    Sc[(size_t)bk * CC + c] = s * inv;
  }
}

// ---------------------------------------------------------------------------
// g4b: CWf[k][j] = sum_c cls[k][c]*Wf[j][c]
// ---------------------------------------------------------------------------
__global__ __launch_bounds__(256) void g4b_cwf(const float* __restrict__ cls,
                                               const float* __restrict__ Wf,
                                               float* __restrict__ CWf) {
  const int k = blockIdx.y;
  const int w = threadIdx.x >> 6, lane = threadIdx.x & 63;
  const int j0 = (blockIdx.x * 4 + w) * 4;
  const float4* arow = (const float4*)(cls + (size_t)k * CC);
  float4 a0 = arow[lane], a1 = arow[64 + lane];
#pragma unroll
  for (int jj = 0; jj < 4; jj++) {
    const float4* brow = (const float4*)(Wf + (size_t)(j0 + jj) * CC);
    float4 b0 = brow[lane], b1 = brow[64 + lane];
    float d = a0.x * b0.x + a0.y * b0.y + a0.z * b0.z + a0.w * b0.w +
              a1.x * b1.x + a1.y * b1.y + a1.z * b1.z + a1.w * b1.w;
#pragma unroll
    for (int o = 32; o > 0; o >>= 1) d += __shfl_down(d, o, 64);
    if (lane == 0) CWf[(size_t)k * CC + j0 + jj] = d;
  }
}

// ---------------------------------------------------------------------------
// g4a: AC[bk][j] = cls[k][j] + sum_c Sc[bk][c]*Wc[j][c]; also writes AC16
// ---------------------------------------------------------------------------
__global__ __launch_bounds__(256) void g4a_ac(const float* __restrict__ Sc,
                                              const float* __restrict__ Wc,
                                              const float* __restrict__ cls,
                                              float* __restrict__ AC,
                                              unsigned short* __restrict__ AC16) {
  const int bk = blockIdx.y;
  const int b = bk / KK, k = bk % KK;
  const int w = threadIdx.x >> 6, lane = threadIdx.x & 63;
  const int j0 = (blockIdx.x * 4 + w) * 4;
  const float4* arow = (const float4*)(Sc + (size_t)bk * CC);
  float4 a0 = arow[lane], a1 = arow[64 + lane];
#pragma unroll
  for (int jj = 0; jj < 4; jj++) {
    const float4* brow = (const float4*)(Wc + (size_t)(j0 + jj) * CC);
    float4 b0 = brow[lane], b1 = brow[64 + lane];
    float d = a0.x * b0.x + a0.y * b0.y + a0.z * b0.z + a0.w * b0.w +
              a1.x * b1.x + a1.y * b1.y + a1.z * b1.z + a1.w * b1.w;
#pragma unroll
    for (int o = 32; o > 0; o >>= 1) d += __shfl_down(d, o, 64);
    if (lane == 0) {
      float val = cls[k * CC + j0 + jj] + d;
      AC[(size_t)bk * CC + j0 + jj] = val;
      AC16[((size_t)b * KP + k) * CC + j0 + jj] = f2b(val);
    }
  }
}

// ---------------------------------------------------------------------------
// g4c: MT16[b][k2][k1] = bf16( exp(rowmax[k1]) * sum_c CWf[k1][c]*AC[b,k2][c] )
// ---------------------------------------------------------------------------
__global__ __launch_bounds__(256) void g4c_m(const float* __restrict__ CWf,
                                             const float* __restrict__ AC,
                                             const float* __restrict__ rowmax,
                                             unsigned short* __restrict__ MT16) {
  const int k1 = blockIdx.y, b = blockIdx.z;
  const int w = threadIdx.x >> 6, lane = threadIdx.x & 63;
  const int k20 = (blockIdx.x * 4 + w) * 4;
  const float4* arow = (const float4*)(CWf + (size_t)k1 * CC);
  float4 a0 = arow[lane], a1 = arow[64 + lane];
  const float u = __expf(rowmax[b * KK + k1]);
#pragma unroll
  for (int jj = 0; jj < 4; jj++) {
    int k2 = k20 + jj;
    if (k2 >= KK) break;
    const float4* brow = (const float4*)(AC + (size_t)(b * KK + k2) * CC);
    float4 b0 = brow[lane], b1 = brow[64 + lane];
    float d = a0.x * b0.x + a0.y * b0.y + a0.z * b0.z + a0.w * b0.w +
              a1.x * b1.x + a1.y * b1.y + a1.z * b1.z + a1.w * b1.w;
#pragma unroll
    for (int o = 32; o > 0; o >>= 1) d += __shfl_down(d, o, 64);
    if (lane == 0) MT16[((size_t)b * KP + k2) * KP + k1] = f2b(d * u);
  }
}

// ---------------------------------------------------------------------------
// g6: masks[k][n] = v[n]*(sum_k' MT'[k][k']*ET[n][k']) + sum_c AC[k][c]*xT[n][c]
//     then LayerNorm over k.  No LDS, no barriers.
// ---------------------------------------------------------------------------
__global__ __launch_bounds__(256) void g6_mfma(
    const unsigned short* __restrict__ xT, const unsigned short* __restrict__ ET,
    const float* __restrict__ vvec, const unsigned short* __restrict__ AC16,
    const unsigned short* __restrict__ MT16, const float* __restrict__ gamma,
    const float* __restrict__ beta, float* __restrict__ out) {
  const int n0 = blockIdx.x * 128, b = blockIdx.y;
  const int tid = threadIdx.x, w = tid >> 6, L = tid & 63;
  const int q = L >> 4, m16 = L & 15;
  f4v zf = {0.f, 0.f, 0.f, 0.f};
  f4v acc[10][2];
#pragma unroll
  for (int mt = 0; mt < 10; mt++) { acc[mt][0] = zf; acc[mt][1] = zf; }

  // ---- part 2: acc = sum_k' MT'[k][k'] * ET[n][k'] ----
  const unsigned short* et0 = ET + ((size_t)(b * HWN + n0 + 32 * w + m16)) * KP + 8 * q;
  const unsigned short* et1 = et0 + 16 * KP;
  const unsigned short* mb = MT16 + (size_t)b * KP * KP + (size_t)m16 * KP + 8 * q;
#pragma unroll
  for (int kc = 0; kc < KP; kc += 32) {
    bf8v b0 = *(const bf8v*)(et0 + kc);
    bf8v b1 = *(const bf8v*)(et1 + kc);
#pragma unroll
    for (int mt = 0; mt < 10; mt++) {
      bf8v a = *(const bf8v*)(mb + (size_t)(16 * mt) * KP + kc);
      acc[mt][0] = __builtin_amdgcn_mfma_f32_16x16x32_bf16(a, b0, acc[mt][0], 0, 0, 0);
      acc[mt][1] = __builtin_amdgcn_mfma_f32_16x16x32_bf16(a, b1, acc[mt][1], 0, 0, 0);
    }
  }
  const float v0 = vvec[b * HWN + n0 + 32 * w + m16];
  const float v1 = vvec[b * HWN + n0 + 32 * w + 16 + m16];
#pragma unroll
  for (int mt = 0; mt < 10; mt++)
#pragma unroll
    for (int r = 0; r < 4; r++) {
      acc[mt][0][r] *= v0;
      acc[mt][1][r] *= v1;
    }

  // ---- part 1: acc += sum_c AC[k][c]*xT[n][c] ----
  const unsigned short* xr0 = xT + ((size_t)(b * HWN + n0 + 32 * w + m16)) * CC + 8 * q;
  const unsigned short* xr1 = xr0 + 16 * CC;
  const unsigned short* ab = AC16 + (size_t)b * KP * CC + (size_t)m16 * CC + 8 * q;
#pragma unroll 2
  for (int c0 = 0; c0 < CC; c0 += 32) {
    bf8v b0 = *(const bf8v*)(xr0 + c0);
    bf8v b1 = *(const bf8v*)(xr1 + c0);
#pragma unroll
    for (int mt = 0; mt < 10; mt++) {
      bf8v a = *(const bf8v*)(ab + (size_t)(16 * mt) * CC + c0);
      acc[mt][0] = __builtin_amdgcn_mfma_f32_16x16x32_bf16(a, b0, acc[mt][0], 0, 0, 0);
      acc[mt][1] = __builtin_amdgcn_mfma_f32_16x16x32_bf16(a, b1, acc[mt][1], 0, 0, 0);
    }
  }

  // ---- LayerNorm over k per n (pad rows are exactly zero) ----
  float s1[2] = {0.f, 0.f}, s2[2] = {0.f, 0.f};
#pragma unroll
  for (int mt = 0; mt < 10; mt++)
#pragma unroll
    for (int r = 0; r < 4; r++)
#pragma unroll
      for (int nc = 0; nc < 2; nc++) {
        float a = acc[mt][nc][r];
        s1[nc] += a;
        s2[nc] += a * a;
      }
#pragma unroll
  for (int nc = 0; nc < 2; nc++) {
    s1[nc] += __shfl_xor(s1[nc], 16, 64);
    s1[nc] += __shfl_xor(s1[nc], 32, 64);
    s2[nc] += __shfl_xor(s2[nc], 16, 64);
    s2[nc] += __shfl_xor(s2[nc], 32, 64);
  }
  float mu[2], inv[2];
#pragma unroll
  for (int nc = 0; nc < 2; nc++) {
    mu[nc] = s1[nc] * (1.0f / KK);
    float var = s2[nc] * (1.0f / KK) - mu[nc] * mu[nc];
    inv[nc] = rsqrtf(var + 1e-5f);
  }
#pragma unroll
  for (int mt = 0; mt < 10; mt++)
#pragma unroll
    for (int r = 0; r < 4; r++) {
      int k = 16 * mt + 4 * q + r;
      if (k < KK) {
        float g = gamma[k], be = beta[k];
        size_t row = (size_t)(b * KK + k) * HWN + n0 + 32 * w;
        out[row + m16] = (acc[mt][0][r] - mu[0]) * inv[0] * g + be;
        out[row + 16 + m16] = (acc[mt][1][r] - mu[1]) * inv[1] * g + be;
      }
    }
}

// ---------------------------------------------------------------------------
extern "C" void kernel_launch(void* const* d_in, const int* in_sizes, int n_in,
                              void* d_out, int out_size, void* d_ws, size_t ws_size,
                              hipStream_t stream) {
  const float* x = (const float*)d_in[0];
  const float* cls = (const float*)d_in[1];
  const float* Wc = (const float*)d_in[2];
  const float* Wf = (const float*)d_in[3];
  const float* gam = (const float*)d_in[4];
  const float* bet = (const float*)d_in[5];
  float* out = (float*)d_out;

  char* p = (char*)d_ws;
  auto alloc = [&](size_t bytes) {
    char* r = p;
    p += (bytes + 255) & ~(size_t)255;
    return r;
  };
  unsigned short* xT16 = (unsigned short*)alloc((size_t)BB * HWN * CC * 2);
  unsigned short* A16 = (unsigned short*)alloc((size_t)BB * KK * HWN * 2);
  unsigned short* E16 = (unsigned short*)alloc((size_t)BB * KP * HWN * 2);
  unsigned short* ET16 = (unsigned short*)alloc((size_t)BB * HWN * KP * 2);
  float* Scp = (float*)alloc((size_t)BB * NSEG * KK * CC * 4);
  float* Sc = (float*)alloc((size_t)BB * KK * CC * 4);
  float* AC = (float*)alloc((size_t)BB * KK * CC * 4);
  unsigned short* AC16 = (unsigned short*)alloc((size_t)BB * KP * CC * 2);
  float* CWf = (float*)alloc((size_t)KK * CC * 4);
  unsigned short* cls16 = (unsigned short*)alloc((size_t)KP * CC * 2);
  unsigned short* MT16 = (unsigned short*)alloc((size_t)BB * KP * KP * 2);
  float* rowmax = (float*)alloc(BB * KK * 4);
  float* rowsum = (float*)alloc(BB * KK * 4);
  float* vvec = (float*)alloc((size_t)BB * HWN * 4);

  t0_prep<<<dim3((BB * KP * KP + 255) / 256), 256, 0, stream>>>(cls, cls16, MT16, AC16);
  t1_transpose<<<dim3(HWN / 64, CC / 32, BB), 256, 0, stream>>>(x, xT16);
  g1_mfma<<<dim3(HWN / 128, BB), 256, 0, stream>>>(xT16, cls16, A16, vvec);
  g2a_rowstats<<<dim3(BB * KK), 256, 0, stream>>>(A16, rowmax, rowsum);
  e1_exp<<<dim3(HWN / 64, KP / 32, BB), 256, 0, stream>>>(A16, rowmax, E16, ET16);
  g3_mfma<<<dim3(CC / 128, NSEG, BB), 256, 0, stream>>>(x, E16, Scp);
  g5_reduce<<<dim3(BB * KK), 256, 0, stream>>>(Scp, rowsum, Sc);
  g4b_cwf<<<dim3(CC / 16, KK), 256, 0, stream>>>(cls, Wf, CWf);
  g4a_ac<<<dim3(CC / 16, BB * KK), 256, 0, stream>>>(Sc, Wc, cls, AC, AC16);
  g4c_m<<<dim3(10, KK, BB), 256, 0, stream>>>(CWf, AC, rowmax, MT16);
  g6_mfma<<<dim3(HWN / 128, BB), 256, 0, stream>>>(xT16, ET16, vvec, AC16, MT16,
                                                   gam, bet, out);
}